// Round 6
// baseline (1515.840 us; speedup 1.0000x reference)
//
#include <hip/hip_runtime.h>
#include <math.h>

// Soft-Viterbi structured decoding: B=32, T=512, N=128, fp32.
// Round 6: BARRIER-FREE. r1/r2/r4/r5 all measured ~1290 cyc/step; ~800 of
// that is stall attributable to the per-step cross-wave s_barrier (4-SIMD
// arrival skew + release) + LDS RT + readlane hazards. This round: ONE WAVE
// per batch (32 blocks x 64 threads) -> no __syncthreads anywhere.
//   * Lane l owns output states (2l, 2l+1).
//   * T split: p<64 half in 128 VGPRs (vf2-packed); p>=64 half in LDS
//     (pair-packed float4: one ds_read_b128 feeds 4 MACs).
//   * alpha/q broadcast: uniform ds_read_b128 from LDS ping-pong;
//     same-wave visibility via lgkmcnt only.
//   * MACs: v_pk_fma_f32 via __builtin_elementwise_fma on float2 vectors
//     (128/step instead of 256 scalar FMA).
//   * r_t = rcp(readlane(Z[0])) - uniform in-wave, stored to sarr for bwd.
//   * em/alpha/p staged in 16-step LDS chunks (off-chain, r5 scheme).
// Recurrences identical to r5 (verified absmax 4.88e-4):
//   fwd: a_t[n] = Z_t[n]*d_t[n]*r_t, Z_t[n] = sum_p Tn[p][n] a_{t-1}[p]
//   bwd: p_t[m] = a_t[m] * sum_n Tn[m][n] q[n],
//        q[n] = p_{t+1}[n]*d_{t+1}[n]*sarr[t+1]/a_{t+1}[n]

#define TT 512
#define BB 32
#define NN 128
#define EPSC 1e-10f

typedef float vf2 __attribute__((ext_vector_type(2)));

__device__ __forceinline__ float rdl0(float v) {
  return __uint_as_float(__builtin_amdgcn_readlane(__float_as_uint(v), 0));
}
__device__ __forceinline__ float rcpf(float v) { return __builtin_amdgcn_rcpf(v); }
__device__ __forceinline__ vf2 fma2(vf2 a, vf2 b, vf2 c) {
  return __builtin_elementwise_fma(a, b, c);
}

__global__ __launch_bounds__(64, 1)
void soft_viterbi_kernel(const float* __restrict__ trans,
                         const float* __restrict__ emis,
                         const float* __restrict__ prior,
                         float* __restrict__ out) {
  const int lane = threadIdx.x;           // 0..63, single wave
  const int n0 = 2 * lane, n1 = n0 + 1;

  __shared__ __align__(16) float TL[32 * 64 * 4];   // 32 KB: T half (fwd p>=64 / bwd k>=64)
  __shared__ __align__(16) float embuf[2][16][NN];  // 16 KB em chunks (by chunk parity)
  __shared__ __align__(16) float xping[2][NN];      // 1 KB alpha/q ping-pong
  __shared__ __align__(16) float ahist[16][NN];     // 8 KB current alpha chunk
  __shared__ __align__(16) float abuf2[2][16][NN];  // 16 KB alpha chunks reloaded (bwd)
  __shared__ __align__(16) float phist[16][NN];     // 8 KB p chunk (bwd)
  __shared__ float sarr[TT];
  __shared__ float red[NN];                          // 1/rowsum

  const float* emb = emis + (size_t)blockIdx.x * TT * NN;
  float* outb = out + (size_t)blockIdx.x * TT * NN;

  // ---- 1/rowsum: lane handles rows n0, n1 ----
  {
    const float4* r0 = (const float4*)(trans + n0 * NN);
    const float4* r1 = (const float4*)(trans + n1 * NN);
    float s0 = 0.f, s1 = 0.f;
    #pragma unroll
    for (int j = 0; j < 32; ++j) {
      float4 a = r0[j], b = r1[j];
      s0 += fmaxf(a.x, EPSC) + fmaxf(a.y, EPSC) + fmaxf(a.z, EPSC) + fmaxf(a.w, EPSC);
      s1 += fmaxf(b.x, EPSC) + fmaxf(b.y, EPSC) + fmaxf(b.z, EPSC) + fmaxf(b.w, EPSC);
    }
    red[n0] = 1.0f / s0;
    red[n1] = 1.0f / s1;
  }

  // ---- forward reg fragment: fa{0,1}[j] = (Tn[2j][n0/1], Tn[2j+1][n0/1]) ----
  vf2 fa0[32], fa1[32];
  #pragma unroll
  for (int j = 0; j < 32; ++j) {
    float2 rA = *(const float2*)(trans + (2 * j) * NN + n0);
    float2 rB = *(const float2*)(trans + (2 * j + 1) * NN + n0);
    const float iA = red[2 * j], iB = red[2 * j + 1];
    fa0[j] = vf2{fmaxf(rA.x, EPSC) * iA, fmaxf(rB.x, EPSC) * iB};
    fa1[j] = vf2{fmaxf(rA.y, EPSC) * iA, fmaxf(rB.y, EPSC) * iB};
  }
  // ---- forward LDS half: TL[j][lane] = (T[64+2j][n0],T[64+2j+1][n0],T[64+2j][n1],T[64+2j+1][n1]) ----
  {
    float4* TL4 = (float4*)TL;
    #pragma unroll
    for (int j = 0; j < 32; ++j) {
      float2 rA = *(const float2*)(trans + (64 + 2 * j) * NN + n0);
      float2 rB = *(const float2*)(trans + (64 + 2 * j + 1) * NN + n0);
      const float iA = red[64 + 2 * j], iB = red[64 + 2 * j + 1];
      TL4[j * 64 + lane] = make_float4(fmaxf(rA.x, EPSC) * iA, fmaxf(rB.x, EPSC) * iB,
                                       fmaxf(rA.y, EPSC) * iA, fmaxf(rB.y, EPSC) * iB);
    }
  }

  // ---- em chunk loader (8 f4 loads + 8 b128 LDS writes) ----
  auto load_em = [&](int c) {
    const float4* src = (const float4*)(emb + c * 16 * NN);
    float4* dst = (float4*)embuf[c & 1];
    #pragma unroll
    for (int j = 0; j < 8; ++j) dst[j * 64 + lane] = src[j * 64 + lane];
  };
  load_em(0);
  load_em(1);

  // ---- alpha_0 ----
  float2 pv = *(const float2*)(prior + n0);
  float p0v = fmaxf(pv.x, EPSC), p1v = fmaxf(pv.y, EPSC);
  float ps = p0v + p1v;
  #pragma unroll
  for (int m = 1; m < 64; m <<= 1) ps += __shfl_xor(ps, m, 64);
  const float pinv = rcpf(ps);
  float2 e0 = *(const float2*)&embuf[0][0][n0];
  float a0 = p0v * pinv * __expf(e0.x);
  float a1 = p1v * pinv * __expf(e0.y);
  *(float2*)&xping[0][n0] = make_float2(a0, a1);
  *(float2*)&ahist[0][n0] = make_float2(a0, a1);
  float2 e1v = *(const float2*)&embuf[0][1][n0];
  float d0 = __expf(e1v.x), d1 = __expf(e1v.y);   // d_1

  // ================= forward (no barriers) =================
  for (int t = 1; t < TT; ++t) {
    if ((t & 15) == 0) {
      const int c = t >> 4;
      { // dump alpha chunk c-1 (rows t-16..t-1)
        const float4* src = (const float4*)ahist;
        float4* dst = (float4*)(outb + (t - 16) * NN);
        #pragma unroll
        for (int j = 0; j < 8; ++j) dst[j * 64 + lane] = src[j * 64 + lane];
      }
      if (c + 1 < 32) load_em(c + 1);
    }
    const float4* ab = (const float4*)xping[(t - 1) & 1];
    vf2 acc0 = {0.f, 0.f}, acc1 = {0.f, 0.f};
    #pragma unroll
    for (int J = 0; J < 16; ++J) {               // p < 64: reg fragment
      float4 av = ab[J];                         // uniform b128 (broadcast)
      acc0 = fma2(vf2{av.x, av.y}, fa0[2 * J], acc0);
      acc1 = fma2(vf2{av.x, av.y}, fa1[2 * J], acc1);
      acc0 = fma2(vf2{av.z, av.w}, fa0[2 * J + 1], acc0);
      acc1 = fma2(vf2{av.z, av.w}, fa1[2 * J + 1], acc1);
    }
    const float4* TL4 = (const float4*)TL;
    #pragma unroll
    for (int J = 0; J < 16; ++J) {               // p >= 64: LDS fragment
      float4 av = ab[16 + J];
      float4 t0v = TL4[(2 * J) * 64 + lane];
      float4 t1v = TL4[(2 * J + 1) * 64 + lane];
      acc0 = fma2(vf2{av.x, av.y}, vf2{t0v.x, t0v.y}, acc0);
      acc1 = fma2(vf2{av.x, av.y}, vf2{t0v.z, t0v.w}, acc1);
      acc0 = fma2(vf2{av.z, av.w}, vf2{t1v.x, t1v.y}, acc0);
      acc1 = fma2(vf2{av.z, av.w}, vf2{t1v.z, t1v.w}, acc1);
    }
    const float Z0 = acc0.x + acc0.y;
    const float Z1 = acc1.x + acc1.y;
    const float r = rcpf(rdl0(Z0));              // uniform, in-wave
    if (lane == 0) sarr[t] = r;
    a0 = Z0 * (d0 * r);
    a1 = Z1 * (d1 * r);
    *(float2*)&xping[t & 1][n0] = make_float2(a0, a1);
    *(float2*)&ahist[t & 15][n0] = make_float2(a0, a1);
    if (t < TT - 1) {                            // d_{t+1}, off-chain
      const int tn = t + 1;
      float2 ev = *(const float2*)&embuf[(tn >> 4) & 1][tn & 15][n0];
      d0 = __expf(ev.x); d1 = __expf(ev.y);
    }
  }
  // d0,d1 = exp(em[511]); a = alpha_511 (ahist chunk 31 NOT dumped - stays in LDS)

  // ================= final softmax =================
  float s = a0 + a1;
  #pragma unroll
  for (int m = 1; m < 64; m <<= 1) s += __shfl_xor(s, m, 64);
  const float isum = rcpf(s);
  const float P0f = a0 * isum, P1f = a1 * isum;  // p_511
  *(float2*)&phist[15][n0] = make_float2(P0f, P1f);

  // ---- rebuild TL for backward: (T[n0][64+2j],T[n0][64+2j+1],T[n1][..],T[n1][..]) ----
  const float i0 = red[n0], i1 = red[n1];
  {
    float4* TL4 = (float4*)TL;
    #pragma unroll
    for (int j = 0; j < 32; ++j) {
      float2 cA = *(const float2*)(trans + n0 * NN + 64 + 2 * j);
      float2 cB = *(const float2*)(trans + n1 * NN + 64 + 2 * j);
      TL4[j * 64 + lane] = make_float4(fmaxf(cA.x, EPSC) * i0, fmaxf(cA.y, EPSC) * i0,
                                       fmaxf(cB.x, EPSC) * i1, fmaxf(cB.y, EPSC) * i1);
    }
  }
  // ---- backward reg fragment: rb{0,1}[j] = (Tn[n0/1][2j], Tn[n0/1][2j+1]) ----
  vf2 rb0[32], rb1[32];
  #pragma unroll
  for (int j = 0; j < 32; ++j) {
    float2 cA = *(const float2*)(trans + n0 * NN + 2 * j);
    float2 cB = *(const float2*)(trans + n1 * NN + 2 * j);
    rb0[j] = vf2{fmaxf(cA.x, EPSC) * i0, fmaxf(cA.y, EPSC) * i0};
    rb1[j] = vf2{fmaxf(cB.x, EPSC) * i1, fmaxf(cB.y, EPSC) * i1};
  }

  // ---- backward init ----
  float q0 = P0f * (d0 * sarr[511]) * rcpf(a0);
  float q1 = P1f * (d1 * sarr[511]) * rcpf(a1);
  *(float2*)&xping[0][n0] = make_float2(q0, q1);   // for t=510 (510&1==0)
  { // prefetch alpha chunk 30 (em chunk 30 already resident in embuf[0])
    const float4* src = (const float4*)(outb + 480 * NN);
    float4* dst = (float4*)abuf2[0];
    #pragma unroll
    for (int j = 0; j < 8; ++j) dst[j * 64 + lane] = src[j * 64 + lane];
  }

  // ================= backward (no barriers) =================
  for (int t = TT - 2; t >= 0; --t) {
    const int c = t >> 4;
    if ((t & 15) == 15 && c >= 1) {   // prefetch alpha+em chunk c-1
      const float4* asrc = (const float4*)(outb + (c - 1) * 16 * NN);
      const float4* esrc = (const float4*)(emb + (c - 1) * 16 * NN);
      float4* adst = (float4*)abuf2[(c - 1) & 1];
      float4* edst = (float4*)embuf[(c - 1) & 1];
      #pragma unroll
      for (int j = 0; j < 8; ++j) {
        adst[j * 64 + lane] = asrc[j * 64 + lane];
        edst[j * 64 + lane] = esrc[j * 64 + lane];
      }
    }
    const float4* qb = (const float4*)xping[t & 1];
    vf2 acc0 = {0.f, 0.f}, acc1 = {0.f, 0.f};
    #pragma unroll
    for (int J = 0; J < 16; ++J) {               // n < 64: reg fragment
      float4 qv = qb[J];
      acc0 = fma2(vf2{qv.x, qv.y}, rb0[2 * J], acc0);
      acc1 = fma2(vf2{qv.x, qv.y}, rb1[2 * J], acc1);
      acc0 = fma2(vf2{qv.z, qv.w}, rb0[2 * J + 1], acc0);
      acc1 = fma2(vf2{qv.z, qv.w}, rb1[2 * J + 1], acc1);
    }
    const float4* TL4 = (const float4*)TL;
    #pragma unroll
    for (int J = 0; J < 16; ++J) {               // n >= 64: LDS fragment
      float4 qv = qb[16 + J];
      float4 t0v = TL4[(2 * J) * 64 + lane];
      float4 t1v = TL4[(2 * J + 1) * 64 + lane];
      acc0 = fma2(vf2{qv.x, qv.y}, vf2{t0v.x, t0v.y}, acc0);
      acc1 = fma2(vf2{qv.x, qv.y}, vf2{t0v.z, t0v.w}, acc1);
      acc0 = fma2(vf2{qv.z, qv.w}, vf2{t1v.x, t1v.y}, acc0);
      acc1 = fma2(vf2{qv.z, qv.w}, vf2{t1v.z, t1v.w}, acc1);
    }
    const float S0 = acc0.x + acc0.y;
    const float S1 = acc1.x + acc1.y;
    float2 av = (c == 31) ? *(const float2*)&ahist[t & 15][n0]
                          : *(const float2*)&abuf2[c & 1][t & 15][n0];
    float2 ev = *(const float2*)&embuf[c & 1][t & 15][n0];
    const float P0 = av.x * S0;                  // p_t
    const float P1 = av.y * S1;
    *(float2*)&phist[t & 15][n0] = make_float2(P0, P1);
    const float st = sarr[t];                    // t=0: garbage, unused below
    q0 = P0 * (__expf(ev.x) * st) * rcpf(av.x);
    q1 = P1 * (__expf(ev.y) * st) * rcpf(av.y);
    if (t > 0) *(float2*)&xping[(t - 1) & 1][n0] = make_float2(q0, q1);
    if ((t & 15) == 0) {                         // dump p chunk c
      const float4* src = (const float4*)phist;
      float4* dst = (float4*)(outb + c * 16 * NN);
      #pragma unroll
      for (int j = 0; j < 8; ++j) dst[j * 64 + lane] = src[j * 64 + lane];
    }
  }
}

extern "C" void kernel_launch(void* const* d_in, const int* in_sizes, int n_in,
                              void* d_out, int out_size, void* d_ws, size_t ws_size,
                              hipStream_t stream) {
  (void)in_sizes; (void)n_in; (void)d_ws; (void)ws_size; (void)out_size;
  const float* trans = (const float*)d_in[0];
  const float* emis  = (const float*)d_in[1];
  const float* prior = (const float*)d_in[2];
  float* out = (float*)d_out;
  soft_viterbi_kernel<<<dim3(BB), dim3(64), 0, stream>>>(trans, emis, prior, out);
}